// Round 1
// baseline (432.683 us; speedup 1.0000x reference)
//
#include <hip/hip_runtime.h>
#include <hip/hip_bf16.h>
#include <math.h>

#define NN 50000
#define NFEAT 256
#define NHID 64
#define NCLASS 40
#define EDGES 800000
#define SCAN_BLK 512

// ---------------- GEMM1: xw = x @ W1  (f32, vector ALU, W1 in LDS) ----------
__global__ __launch_bounds__(256) void k_gemm1(const float* __restrict__ x,
                                               const float* __restrict__ W1,
                                               float* __restrict__ xw) {
    __shared__ float Wld[NFEAT * NHID];   // 64 KB
    const float4* W4 = (const float4*)W1;
    float4* Wld4 = (float4*)Wld;
    for (int i = threadIdx.x; i < NFEAT * NHID / 4; i += 256) Wld4[i] = W4[i];
    __syncthreads();

    const int lane = threadIdx.x & 63;
    const int wid  = threadIdx.x >> 6;
    const int gw   = blockIdx.x * 4 + wid;
    const int nw   = gridDim.x * 4;

    for (int r0 = gw * 2; r0 < NN; r0 += nw * 2) {
        const int ra = __builtin_amdgcn_readfirstlane(r0);
        const int rb = ra + 1;                       // NN even -> always valid
        const float* __restrict__ xa = x + (size_t)ra * NFEAT;
        const float* __restrict__ xb = x + (size_t)rb * NFEAT;
        float acc0 = 0.f, acc1 = 0.f;
        #pragma unroll 4
        for (int k = 0; k < NFEAT; ++k) {
            float w = Wld[k * NHID + lane];
            acc0 += xa[k] * w;
            acc1 += xb[k] * w;
        }
        xw[(size_t)ra * NHID + lane] = acc0;
        xw[(size_t)rb * NHID + lane] = acc1;
    }
}

// ---------------- CSR build ------------------------------------------------
__global__ void k_zero(int* __restrict__ count) {
    int i = blockIdx.x * 256 + threadIdx.x;
    if (i < NN) count[i] = 0;
}

__global__ void k_hist(const int* __restrict__ dst, int* __restrict__ count) {
    int e = blockIdx.x * 256 + threadIdx.x;
    if (e < EDGES) atomicAdd(&count[dst[e]], 1);
}

__global__ __launch_bounds__(SCAN_BLK) void k_scanA(const int* __restrict__ count,
                                                    int* __restrict__ tmp,
                                                    int* __restrict__ blocksum) {
    __shared__ int s[SCAN_BLK];
    int i = blockIdx.x * SCAN_BLK + threadIdx.x;
    int v = (i < NN) ? count[i] : 0;
    s[threadIdx.x] = v;
    __syncthreads();
    for (int off = 1; off < SCAN_BLK; off <<= 1) {
        int t = (threadIdx.x >= off) ? s[threadIdx.x - off] : 0;
        __syncthreads();
        s[threadIdx.x] += t;
        __syncthreads();
    }
    if (i < NN) tmp[i] = s[threadIdx.x];
    if (threadIdx.x == SCAN_BLK - 1) blocksum[blockIdx.x] = s[SCAN_BLK - 1];
}

__global__ void k_scanB(const int* __restrict__ blocksum, int* __restrict__ blockoff, int nb) {
    __shared__ int s[128];
    int v = (threadIdx.x < nb) ? blocksum[threadIdx.x] : 0;
    s[threadIdx.x] = v;
    __syncthreads();
    for (int off = 1; off < 128; off <<= 1) {
        int t = (threadIdx.x >= off) ? s[threadIdx.x - off] : 0;
        __syncthreads();
        s[threadIdx.x] += t;
        __syncthreads();
    }
    if (threadIdx.x < nb) blockoff[threadIdx.x] = s[threadIdx.x] - v;  // exclusive
}

__global__ void k_scanC(const int* __restrict__ tmp, const int* __restrict__ blockoff,
                        const int* __restrict__ count,
                        int* __restrict__ row_ptr, int* __restrict__ cursor) {
    int i = blockIdx.x * 256 + threadIdx.x;
    if (i < NN) {
        int incl = tmp[i] + blockoff[i / SCAN_BLK];
        row_ptr[i + 1] = incl;
        cursor[i] = incl - count[i];
        if (i == 0) row_ptr[0] = 0;
    }
}

__global__ void k_scatter(const int* __restrict__ src, const int* __restrict__ dst,
                          const float* __restrict__ val, int* __restrict__ cursor,
                          int* __restrict__ csr_col, float* __restrict__ csr_val) {
    int e = blockIdx.x * 256 + threadIdx.x;
    if (e < EDGES) {
        int p = atomicAdd(&cursor[dst[e]], 1);
        csr_col[p] = src[e];
        csr_val[p] = val[e];
    }
}

// ---------------- SPMM: out[r,:] = sum_j val_j * in[col_j,:]  (d=64) --------
template <bool RELU>
__global__ __launch_bounds__(256) void k_spmm(const float* __restrict__ in,
                                              const int* __restrict__ row_ptr,
                                              const int* __restrict__ col,
                                              const float* __restrict__ val,
                                              const float* __restrict__ bias,
                                              float* __restrict__ out) {
    const int lane = threadIdx.x & 63;
    int gw = (blockIdx.x * 256 + threadIdx.x) >> 6;
    if (gw >= NN) return;
    const int r   = __builtin_amdgcn_readfirstlane(gw);
    const int beg = row_ptr[r];
    const int end = row_ptr[r + 1];

    float acc = 0.f;
    int j = beg;
    for (; j + 3 < end; j += 4) {
        int   s0 = col[j],     s1 = col[j + 1], s2 = col[j + 2], s3 = col[j + 3];
        float v0 = val[j],     v1 = val[j + 1], v2 = val[j + 2], v3 = val[j + 3];
        acc += v0 * in[(size_t)s0 * NHID + lane];
        acc += v1 * in[(size_t)s1 * NHID + lane];
        acc += v2 * in[(size_t)s2 * NHID + lane];
        acc += v3 * in[(size_t)s3 * NHID + lane];
    }
    for (; j < end; ++j) acc += val[j] * in[(size_t)col[j] * NHID + lane];

    if (RELU)
        out[(size_t)r * NHID + lane] = fmaxf(acc + bias[lane], 0.f);
    else
        out[(size_t)r * NHID + lane] = acc;
}

// ---------------- Fused epilogue: heads + reparam + log_softmax -------------
__global__ __launch_bounds__(256) void k_final(const float* __restrict__ g2,
                                               const float* __restrict__ W11,
                                               const float* __restrict__ b11,
                                               const float* __restrict__ W12,
                                               const float* __restrict__ b12,
                                               const float* __restrict__ eps,
                                               float* __restrict__ out) {
    __shared__ float W11l[NHID * NCLASS];
    __shared__ float W12l[NHID * NCLASS];
    __shared__ float bl[2 * NCLASS];
    for (int i = threadIdx.x; i < NHID * NCLASS; i += 256) {
        W11l[i] = W11[i];
        W12l[i] = W12[i];
    }
    if (threadIdx.x < NCLASS) bl[threadIdx.x] = b11[threadIdx.x];
    else if (threadIdx.x < 2 * NCLASS) bl[threadIdx.x] = b12[threadIdx.x - NCLASS];
    __syncthreads();

    const int lane = threadIdx.x & 63;
    const int gw   = (blockIdx.x * 256 + threadIdx.x) >> 6;
    const int nw   = gridDim.x * 4;
    const bool act = lane < NCLASS;
    const int  cc  = act ? lane : NCLASS - 1;

    for (int r = gw; r < NN; r += nw) {
        const int ur = __builtin_amdgcn_readfirstlane(r);
        const float* __restrict__ g = g2 + (size_t)ur * NHID;
        float m  = bl[cc];
        float lg = bl[NCLASS + cc];
        #pragma unroll 8
        for (int k = 0; k < NHID; ++k) {
            float gv = g[k];
            m  += gv * W11l[k * NCLASS + cc];
            lg += gv * W12l[k * NCLASS + cc];
        }
        float z = act ? (eps[(size_t)ur * NCLASS + lane] * expf(lg) + m) : -1e30f;

        float zmax = z;
        #pragma unroll
        for (int off = 32; off >= 1; off >>= 1) zmax = fmaxf(zmax, __shfl_xor(zmax, off));
        float ez = act ? expf(z - zmax) : 0.f;
        float s = ez;
        #pragma unroll
        for (int off = 32; off >= 1; off >>= 1) s += __shfl_xor(s, off);

        if (act) out[(size_t)ur * NCLASS + lane] = z - zmax - logf(s);
    }
}

// ---------------- launcher --------------------------------------------------
extern "C" void kernel_launch(void* const* d_in, const int* in_sizes, int n_in,
                              void* d_out, int out_size, void* d_ws, size_t ws_size,
                              hipStream_t stream) {
    const float* x        = (const float*)d_in[0];
    const int*   edge_src = (const int*)d_in[1];
    const int*   edge_dst = (const int*)d_in[2];
    const float* edge_val = (const float*)d_in[3];
    const float* eps      = (const float*)d_in[4];
    const float* W1       = (const float*)d_in[5];
    const float* b1       = (const float*)d_in[6];
    const float* W11      = (const float*)d_in[7];
    const float* b11      = (const float*)d_in[8];
    const float* W12      = (const float*)d_in[9];
    const float* b12      = (const float*)d_in[10];
    float* out = (float*)d_out;

    // workspace layout (g2 aliases xw — xw is dead after spmm1)
    float* xw      = (float*)d_ws;                 // NN*64
    float* h       = xw + (size_t)NN * NHID;       // NN*64
    int*   count   = (int*)(h + (size_t)NN * NHID);
    int*   tmp     = count + NN;
    int*   row_ptr = tmp + NN;                     // NN+1
    int*   cursor  = row_ptr + (NN + 1);
    int*   blocksum= cursor + NN;
    int*   blockoff= blocksum + 128;
    int*   csr_col = blockoff + 128;               // EDGES
    float* csr_val = (float*)(csr_col + EDGES);    // EDGES
    float* g2 = xw;

    const int NB = (NN + SCAN_BLK - 1) / SCAN_BLK; // 98

    k_gemm1<<<1024, 256, 0, stream>>>(x, W1, xw);
    k_zero<<<(NN + 255) / 256, 256, 0, stream>>>(count);
    k_hist<<<(EDGES + 255) / 256, 256, 0, stream>>>(edge_dst, count);
    k_scanA<<<NB, SCAN_BLK, 0, stream>>>(count, tmp, blocksum);
    k_scanB<<<1, 128, 0, stream>>>(blocksum, blockoff, NB);
    k_scanC<<<(NN + 255) / 256, 256, 0, stream>>>(tmp, blockoff, count, row_ptr, cursor);
    k_scatter<<<(EDGES + 255) / 256, 256, 0, stream>>>(edge_src, edge_dst, edge_val,
                                                       cursor, csr_col, csr_val);
    k_spmm<true><<<NN / 4, 256, 0, stream>>>(xw, row_ptr, csr_col, csr_val, b1, h);
    k_spmm<false><<<NN / 4, 256, 0, stream>>>(h, row_ptr, csr_col, csr_val, nullptr, g2);
    k_final<<<2048, 256, 0, stream>>>(g2, W11, b11, W12, b12, eps, out);
}

// Round 2
// 310.292 us; speedup vs baseline: 1.3944x; 1.3944x over previous
//
#include <hip/hip_runtime.h>
#include <hip/hip_bf16.h>
#include <math.h>

#define NN 50000
#define NFEAT 256
#define NHID 64
#define NCLASS 40
#define EDGES 800000
#define SCAN_BLK 512

// ---------------- GEMM1: xw = x @ W1  (f32 tiled, 64x64 tile, 4x4 microtile) ----
// Block: 256 threads = 16x16; each thread owns a 4x4 output microtile.
// LDS: xs transposed [BK][BM+4] so a-frag is a broadcast float4; ws row-major.
#define BM 64
#define BK 32
__global__ __launch_bounds__(256) void k_gemm1(const float* __restrict__ x,
                                               const float* __restrict__ W1,
                                               float* __restrict__ xw) {
    __shared__ float xs[BK][BM + 4];   // +4 pad keeps 16B alignment, spreads banks
    __shared__ float ws[BK][NHID];
    const int tid = threadIdx.x;
    const int tx  = tid & 15;          // col group (4 cols each)
    const int ty  = tid >> 4;          // row group (4 rows each)
    const int r0  = blockIdx.x * BM;

    float acc[4][4] = {};

    for (int kc = 0; kc < NFEAT; kc += BK) {
        // x tile: rows r0..r0+63, k kc..kc+31 (2048 floats, 2 passes of 256xfloat4)
        #pragma unroll
        for (int p = 0; p < 2; ++p) {
            int e   = tid * 4 + p * 1024;
            int row = e >> 5;          // 0..63
            int k   = e & 31;
            int gr  = r0 + row;
            float4 v = make_float4(0.f, 0.f, 0.f, 0.f);
            if (gr < NN) v = *(const float4*)&x[(size_t)gr * NFEAT + kc + k];
            xs[k + 0][row] = v.x; xs[k + 1][row] = v.y;
            xs[k + 2][row] = v.z; xs[k + 3][row] = v.w;
        }
        // W tile: k kc..kc+31, all 64 cols (2048 floats)
        #pragma unroll
        for (int p = 0; p < 2; ++p) {
            int e  = tid * 4 + p * 1024;
            int kk = e >> 6;
            int c  = e & 63;
            *(float4*)&ws[kk][c] = *(const float4*)&W1[(size_t)(kc + kk) * NHID + c];
        }
        __syncthreads();
        #pragma unroll
        for (int kk = 0; kk < BK; ++kk) {
            float4 a = *(const float4*)&xs[kk][ty * 4];
            float4 b = *(const float4*)&ws[kk][tx * 4];
            acc[0][0] += a.x * b.x; acc[0][1] += a.x * b.y; acc[0][2] += a.x * b.z; acc[0][3] += a.x * b.w;
            acc[1][0] += a.y * b.x; acc[1][1] += a.y * b.y; acc[1][2] += a.y * b.z; acc[1][3] += a.y * b.w;
            acc[2][0] += a.z * b.x; acc[2][1] += a.z * b.y; acc[2][2] += a.z * b.z; acc[2][3] += a.z * b.w;
            acc[3][0] += a.w * b.x; acc[3][1] += a.w * b.y; acc[3][2] += a.w * b.z; acc[3][3] += a.w * b.w;
        }
        __syncthreads();
    }
    #pragma unroll
    for (int i = 0; i < 4; ++i) {
        int gr = r0 + ty * 4 + i;
        if (gr < NN)
            *(float4*)&xw[(size_t)gr * NHID + tx * 4] =
                make_float4(acc[i][0], acc[i][1], acc[i][2], acc[i][3]);
    }
}

// ---------------- CSR build ------------------------------------------------
__global__ void k_zero(int* __restrict__ count) {
    int i = blockIdx.x * 256 + threadIdx.x;
    if (i < NN) count[i] = 0;
}

__global__ void k_hist(const int* __restrict__ dst, int* __restrict__ count) {
    int e = blockIdx.x * 256 + threadIdx.x;
    if (e < EDGES) atomicAdd(&count[dst[e]], 1);
}

__global__ __launch_bounds__(SCAN_BLK) void k_scanA(const int* __restrict__ count,
                                                    int* __restrict__ tmp,
                                                    int* __restrict__ blocksum) {
    __shared__ int s[SCAN_BLK];
    int i = blockIdx.x * SCAN_BLK + threadIdx.x;
    int v = (i < NN) ? count[i] : 0;
    s[threadIdx.x] = v;
    __syncthreads();
    for (int off = 1; off < SCAN_BLK; off <<= 1) {
        int t = (threadIdx.x >= off) ? s[threadIdx.x - off] : 0;
        __syncthreads();
        s[threadIdx.x] += t;
        __syncthreads();
    }
    if (i < NN) tmp[i] = s[threadIdx.x];
    if (threadIdx.x == SCAN_BLK - 1) blocksum[blockIdx.x] = s[SCAN_BLK - 1];
}

__global__ void k_scanB(const int* __restrict__ blocksum, int* __restrict__ blockoff, int nb) {
    __shared__ int s[128];
    int v = (threadIdx.x < nb) ? blocksum[threadIdx.x] : 0;
    s[threadIdx.x] = v;
    __syncthreads();
    for (int off = 1; off < 128; off <<= 1) {
        int t = (threadIdx.x >= off) ? s[threadIdx.x - off] : 0;
        __syncthreads();
        s[threadIdx.x] += t;
        __syncthreads();
    }
    if (threadIdx.x < nb) blockoff[threadIdx.x] = s[threadIdx.x] - v;  // exclusive
}

__global__ void k_scanC(const int* __restrict__ tmp, const int* __restrict__ blockoff,
                        const int* __restrict__ count,
                        int* __restrict__ row_ptr, int* __restrict__ cursor) {
    int i = blockIdx.x * 256 + threadIdx.x;
    if (i < NN) {
        int incl = tmp[i] + blockoff[i / SCAN_BLK];
        row_ptr[i + 1] = incl;
        cursor[i] = incl - count[i];
        if (i == 0) row_ptr[0] = 0;
    }
}

__global__ void k_scatter(const int* __restrict__ src, const int* __restrict__ dst,
                          const float* __restrict__ val, int* __restrict__ cursor,
                          int* __restrict__ csr_col, float* __restrict__ csr_val) {
    int e = blockIdx.x * 256 + threadIdx.x;
    if (e < EDGES) {
        int p = atomicAdd(&cursor[dst[e]], 1);
        csr_col[p] = src[e];
        csr_val[p] = val[e];
    }
}

// ---------------- SPMM: out[r,:] = sum_j val_j * in[col_j,:]  (d=64) --------
template <bool RELU>
__global__ __launch_bounds__(256) void k_spmm(const float* __restrict__ in,
                                              const int* __restrict__ row_ptr,
                                              const int* __restrict__ col,
                                              const float* __restrict__ val,
                                              const float* __restrict__ bias,
                                              float* __restrict__ out) {
    const int lane = threadIdx.x & 63;
    int gw = (blockIdx.x * 256 + threadIdx.x) >> 6;
    if (gw >= NN) return;
    const int r   = __builtin_amdgcn_readfirstlane(gw);
    const int beg = row_ptr[r];
    const int end = row_ptr[r + 1];

    float acc = 0.f;
    int j = beg;
    for (; j + 3 < end; j += 4) {
        int   s0 = col[j],     s1 = col[j + 1], s2 = col[j + 2], s3 = col[j + 3];
        float v0 = val[j],     v1 = val[j + 1], v2 = val[j + 2], v3 = val[j + 3];
        acc += v0 * in[(size_t)s0 * NHID + lane];
        acc += v1 * in[(size_t)s1 * NHID + lane];
        acc += v2 * in[(size_t)s2 * NHID + lane];
        acc += v3 * in[(size_t)s3 * NHID + lane];
    }
    for (; j < end; ++j) acc += val[j] * in[(size_t)col[j] * NHID + lane];

    if (RELU)
        out[(size_t)r * NHID + lane] = fmaxf(acc + bias[lane], 0.f);
    else
        out[(size_t)r * NHID + lane] = acc;
}

// ---------------- Fused epilogue: heads + reparam + log_softmax -------------
// One wave per 4 consecutive rows: W-LDS reads amortized 4x, 8 indep FMA chains.
__global__ __launch_bounds__(256) void k_final(const float* __restrict__ g2,
                                               const float* __restrict__ W11,
                                               const float* __restrict__ b11,
                                               const float* __restrict__ W12,
                                               const float* __restrict__ b12,
                                               const float* __restrict__ eps,
                                               float* __restrict__ out) {
    __shared__ float W11l[NHID * NCLASS];
    __shared__ float W12l[NHID * NCLASS];
    __shared__ float bl[2 * NCLASS];
    for (int i = threadIdx.x; i < NHID * NCLASS; i += 256) {
        W11l[i] = W11[i];
        W12l[i] = W12[i];
    }
    if (threadIdx.x < NCLASS) bl[threadIdx.x] = b11[threadIdx.x];
    else if (threadIdx.x < 2 * NCLASS) bl[threadIdx.x] = b12[threadIdx.x - NCLASS];
    __syncthreads();

    const int lane = threadIdx.x & 63;
    const int gw   = (blockIdx.x * 256 + threadIdx.x) >> 6;  // 12500 waves exactly
    const bool act = lane < NCLASS;
    const int  cc  = act ? lane : NCLASS - 1;

    const int r0 = gw * 4;
    if (r0 >= NN) return;
    const int ur = __builtin_amdgcn_readfirstlane(r0);
    const float* __restrict__ g = g2 + (size_t)ur * NHID;   // 4 consecutive rows

    float m[4], lg[4];
    #pragma unroll
    for (int i = 0; i < 4; ++i) { m[i] = bl[cc]; lg[i] = bl[NCLASS + cc]; }

    #pragma unroll 4
    for (int k = 0; k < NHID; ++k) {
        float w1 = W11l[k * NCLASS + cc];
        float w2 = W12l[k * NCLASS + cc];
        float ga = g[k], gb = g[NHID + k], gc = g[2 * NHID + k], gd = g[3 * NHID + k];
        m[0] += ga * w1; lg[0] += ga * w2;
        m[1] += gb * w1; lg[1] += gb * w2;
        m[2] += gc * w1; lg[2] += gc * w2;
        m[3] += gd * w1; lg[3] += gd * w2;
    }

    float z[4];
    #pragma unroll
    for (int i = 0; i < 4; ++i)
        z[i] = act ? (eps[(size_t)(ur + i) * NCLASS + lane] * expf(lg[i]) + m[i]) : -1e30f;

    float zmax[4], s[4];
    #pragma unroll
    for (int i = 0; i < 4; ++i) zmax[i] = z[i];
    #pragma unroll
    for (int off = 32; off >= 1; off >>= 1) {
        #pragma unroll
        for (int i = 0; i < 4; ++i) zmax[i] = fmaxf(zmax[i], __shfl_xor(zmax[i], off));
    }
    #pragma unroll
    for (int i = 0; i < 4; ++i) s[i] = act ? expf(z[i] - zmax[i]) : 0.f;
    #pragma unroll
    for (int off = 32; off >= 1; off >>= 1) {
        #pragma unroll
        for (int i = 0; i < 4; ++i) s[i] += __shfl_xor(s[i], off);
    }
    if (act) {
        #pragma unroll
        for (int i = 0; i < 4; ++i)
            out[(size_t)(ur + i) * NCLASS + lane] = z[i] - zmax[i] - logf(s[i]);
    }
}

// ---------------- launcher --------------------------------------------------
extern "C" void kernel_launch(void* const* d_in, const int* in_sizes, int n_in,
                              void* d_out, int out_size, void* d_ws, size_t ws_size,
                              hipStream_t stream) {
    const float* x        = (const float*)d_in[0];
    const int*   edge_src = (const int*)d_in[1];
    const int*   edge_dst = (const int*)d_in[2];
    const float* edge_val = (const float*)d_in[3];
    const float* eps      = (const float*)d_in[4];
    const float* W1       = (const float*)d_in[5];
    const float* b1       = (const float*)d_in[6];
    const float* W11      = (const float*)d_in[7];
    const float* b11      = (const float*)d_in[8];
    const float* W12      = (const float*)d_in[9];
    const float* b12      = (const float*)d_in[10];
    float* out = (float*)d_out;

    // workspace layout (g2 aliases xw — xw is dead after spmm1)
    float* xw      = (float*)d_ws;                 // NN*64
    float* h       = xw + (size_t)NN * NHID;       // NN*64
    int*   count   = (int*)(h + (size_t)NN * NHID);
    int*   tmp     = count + NN;
    int*   row_ptr = tmp + NN;                     // NN+1
    int*   cursor  = row_ptr + (NN + 1);
    int*   blocksum= cursor + NN;
    int*   blockoff= blocksum + 128;
    int*   csr_col = blockoff + 128;               // EDGES
    float* csr_val = (float*)(csr_col + EDGES);    // EDGES
    float* g2 = xw;

    const int NB = (NN + SCAN_BLK - 1) / SCAN_BLK; // 98

    k_gemm1<<<(NN + BM - 1) / BM, 256, 0, stream>>>(x, W1, xw);
    k_zero<<<(NN + 255) / 256, 256, 0, stream>>>(count);
    k_hist<<<(EDGES + 255) / 256, 256, 0, stream>>>(edge_dst, count);
    k_scanA<<<NB, SCAN_BLK, 0, stream>>>(count, tmp, blocksum);
    k_scanB<<<1, 128, 0, stream>>>(blocksum, blockoff, NB);
    k_scanC<<<(NN + 255) / 256, 256, 0, stream>>>(tmp, blockoff, count, row_ptr, cursor);
    k_scatter<<<(EDGES + 255) / 256, 256, 0, stream>>>(edge_src, edge_dst, edge_val,
                                                       cursor, csr_col, csr_val);
    k_spmm<true><<<NN / 4, 256, 0, stream>>>(xw, row_ptr, csr_col, csr_val, b1, h);
    k_spmm<false><<<NN / 4, 256, 0, stream>>>(h, row_ptr, csr_col, csr_val, nullptr, g2);
    k_final<<<(NN / 4 + 3) / 4, 256, 0, stream>>>(g2, W11, b11, W12, b12, eps, out);
}

// Round 3
// 309.744 us; speedup vs baseline: 1.3969x; 1.0018x over previous
//
#include <hip/hip_runtime.h>
#include <hip/hip_bf16.h>
#include <math.h>

#define NN 50000
#define NFEAT 256
#define NHID 64
#define NCLASS 40
#define EDGES 800000
#define SCAN_BLK 512

// ---------------- GEMM1: xw = x @ W1  (f32 tiled, 64x64 tile, 4x4 microtile) ----
#define BM 64
#define BK 32
__global__ __launch_bounds__(256) void k_gemm1(const float* __restrict__ x,
                                               const float* __restrict__ W1,
                                               float* __restrict__ xw) {
    __shared__ float xs[BK][BM + 4];
    __shared__ float ws[BK][NHID];
    const int tid = threadIdx.x;
    const int tx  = tid & 15;
    const int ty  = tid >> 4;
    const int r0  = blockIdx.x * BM;

    float acc[4][4] = {};

    for (int kc = 0; kc < NFEAT; kc += BK) {
        #pragma unroll
        for (int p = 0; p < 2; ++p) {
            int e   = tid * 4 + p * 1024;
            int row = e >> 5;
            int k   = e & 31;
            int gr  = r0 + row;
            float4 v = make_float4(0.f, 0.f, 0.f, 0.f);
            if (gr < NN) v = *(const float4*)&x[(size_t)gr * NFEAT + kc + k];
            xs[k + 0][row] = v.x; xs[k + 1][row] = v.y;
            xs[k + 2][row] = v.z; xs[k + 3][row] = v.w;
        }
        #pragma unroll
        for (int p = 0; p < 2; ++p) {
            int e  = tid * 4 + p * 1024;
            int kk = e >> 6;
            int c  = e & 63;
            *(float4*)&ws[kk][c] = *(const float4*)&W1[(size_t)(kc + kk) * NHID + c];
        }
        __syncthreads();
        #pragma unroll
        for (int kk = 0; kk < BK; ++kk) {
            float4 a = *(const float4*)&xs[kk][ty * 4];
            float4 b = *(const float4*)&ws[kk][tx * 4];
            acc[0][0] += a.x * b.x; acc[0][1] += a.x * b.y; acc[0][2] += a.x * b.z; acc[0][3] += a.x * b.w;
            acc[1][0] += a.y * b.x; acc[1][1] += a.y * b.y; acc[1][2] += a.y * b.z; acc[1][3] += a.y * b.w;
            acc[2][0] += a.z * b.x; acc[2][1] += a.z * b.y; acc[2][2] += a.z * b.z; acc[2][3] += a.z * b.w;
            acc[3][0] += a.w * b.x; acc[3][1] += a.w * b.y; acc[3][2] += a.w * b.z; acc[3][3] += a.w * b.w;
        }
        __syncthreads();
    }
    #pragma unroll
    for (int i = 0; i < 4; ++i) {
        int gr = r0 + ty * 4 + i;
        if (gr < NN)
            *(float4*)&xw[(size_t)gr * NHID + tx * 4] =
                make_float4(acc[i][0], acc[i][1], acc[i][2], acc[i][3]);
    }
}

// ---------------- CSR build ------------------------------------------------
__global__ void k_zero(int* __restrict__ count) {
    int i = blockIdx.x * 256 + threadIdx.x;
    if (i < NN) count[i] = 0;
}

// 4 edges per thread via int4 load
__global__ void k_hist(const int* __restrict__ dst, int* __restrict__ count) {
    int t = blockIdx.x * 256 + threadIdx.x;
    if (t < EDGES / 4) {
        int4 d = ((const int4*)dst)[t];
        atomicAdd(&count[d.x], 1);
        atomicAdd(&count[d.y], 1);
        atomicAdd(&count[d.z], 1);
        atomicAdd(&count[d.w], 1);
    }
}

__global__ __launch_bounds__(SCAN_BLK) void k_scanA(const int* __restrict__ count,
                                                    int* __restrict__ tmp,
                                                    int* __restrict__ blocksum) {
    __shared__ int s[SCAN_BLK];
    int i = blockIdx.x * SCAN_BLK + threadIdx.x;
    int v = (i < NN) ? count[i] : 0;
    s[threadIdx.x] = v;
    __syncthreads();
    for (int off = 1; off < SCAN_BLK; off <<= 1) {
        int t = (threadIdx.x >= off) ? s[threadIdx.x - off] : 0;
        __syncthreads();
        s[threadIdx.x] += t;
        __syncthreads();
    }
    if (i < NN) tmp[i] = s[threadIdx.x];
    if (threadIdx.x == SCAN_BLK - 1) blocksum[blockIdx.x] = s[SCAN_BLK - 1];
}

__global__ void k_scanB(const int* __restrict__ blocksum, int* __restrict__ blockoff, int nb) {
    __shared__ int s[128];
    int v = (threadIdx.x < nb) ? blocksum[threadIdx.x] : 0;
    s[threadIdx.x] = v;
    __syncthreads();
    for (int off = 1; off < 128; off <<= 1) {
        int t = (threadIdx.x >= off) ? s[threadIdx.x - off] : 0;
        __syncthreads();
        s[threadIdx.x] += t;
        __syncthreads();
    }
    if (threadIdx.x < nb) blockoff[threadIdx.x] = s[threadIdx.x] - v;  // exclusive
}

__global__ void k_scanC(const int* __restrict__ tmp, const int* __restrict__ blockoff,
                        const int* __restrict__ count,
                        int* __restrict__ row_ptr, int* __restrict__ cursor) {
    int i = blockIdx.x * 256 + threadIdx.x;
    if (i < NN) {
        int incl = tmp[i] + blockoff[i / SCAN_BLK];
        row_ptr[i + 1] = incl;
        cursor[i] = incl - count[i];
        if (i == 0) row_ptr[0] = 0;
    }
}

// packed (col,val) single 8B store: halves scattered cacheline touches
__global__ void k_scatter(const int* __restrict__ src, const int* __restrict__ dst,
                          const float* __restrict__ val, int* __restrict__ cursor,
                          int2* __restrict__ csr) {
    int e = blockIdx.x * 256 + threadIdx.x;
    if (e < EDGES) {
        int p = atomicAdd(&cursor[dst[e]], 1);
        int2 cv;
        cv.x = src[e];
        cv.y = __float_as_int(val[e]);
        csr[p] = cv;
    }
}

// ---------------- SPMM: out[r,:] = sum_j val_j * in[col_j,:]  (d=64) --------
template <bool RELU>
__global__ __launch_bounds__(256) void k_spmm(const float* __restrict__ in,
                                              const int* __restrict__ row_ptr,
                                              const int2* __restrict__ csr,
                                              const float* __restrict__ bias,
                                              float* __restrict__ out) {
    const int lane = threadIdx.x & 63;
    int gw = (blockIdx.x * 256 + threadIdx.x) >> 6;
    if (gw >= NN) return;
    const int r   = __builtin_amdgcn_readfirstlane(gw);
    const int beg = row_ptr[r];
    const int end = row_ptr[r + 1];

    float acc0 = 0.f, acc1 = 0.f;
    int j = beg;
    for (; j + 3 < end; j += 4) {
        int2 a = csr[j], b = csr[j + 1], c = csr[j + 2], d = csr[j + 3];
        acc0 += __int_as_float(a.y) * in[(size_t)a.x * NHID + lane];
        acc1 += __int_as_float(b.y) * in[(size_t)b.x * NHID + lane];
        acc0 += __int_as_float(c.y) * in[(size_t)c.x * NHID + lane];
        acc1 += __int_as_float(d.y) * in[(size_t)d.x * NHID + lane];
    }
    for (; j < end; ++j) {
        int2 a = csr[j];
        acc0 += __int_as_float(a.y) * in[(size_t)a.x * NHID + lane];
    }
    float acc = acc0 + acc1;

    if (RELU)
        out[(size_t)r * NHID + lane] = fmaxf(acc + bias[lane], 0.f);
    else
        out[(size_t)r * NHID + lane] = acc;
}

// ---------------- Fused epilogue: heads + reparam + log_softmax -------------
__global__ __launch_bounds__(256) void k_final(const float* __restrict__ g2,
                                               const float* __restrict__ W11,
                                               const float* __restrict__ b11,
                                               const float* __restrict__ W12,
                                               const float* __restrict__ b12,
                                               const float* __restrict__ eps,
                                               float* __restrict__ out) {
    __shared__ float W11l[NHID * NCLASS];
    __shared__ float W12l[NHID * NCLASS];
    __shared__ float bl[2 * NCLASS];
    for (int i = threadIdx.x; i < NHID * NCLASS; i += 256) {
        W11l[i] = W11[i];
        W12l[i] = W12[i];
    }
    if (threadIdx.x < NCLASS) bl[threadIdx.x] = b11[threadIdx.x];
    else if (threadIdx.x < 2 * NCLASS) bl[threadIdx.x] = b12[threadIdx.x - NCLASS];
    __syncthreads();

    const int lane = threadIdx.x & 63;
    const int gw   = (blockIdx.x * 256 + threadIdx.x) >> 6;
    const bool act = lane < NCLASS;
    const int  cc  = act ? lane : NCLASS - 1;

    const int r0 = gw * 4;
    if (r0 >= NN) return;
    const int ur = __builtin_amdgcn_readfirstlane(r0);
    const float* __restrict__ g = g2 + (size_t)ur * NHID;

    float m[4], lg[4];
    #pragma unroll
    for (int i = 0; i < 4; ++i) { m[i] = bl[cc]; lg[i] = bl[NCLASS + cc]; }

    #pragma unroll 4
    for (int k = 0; k < NHID; ++k) {
        float w1 = W11l[k * NCLASS + cc];
        float w2 = W12l[k * NCLASS + cc];
        float ga = g[k], gb = g[NHID + k], gc = g[2 * NHID + k], gd = g[3 * NHID + k];
        m[0] += ga * w1; lg[0] += ga * w2;
        m[1] += gb * w1; lg[1] += gb * w2;
        m[2] += gc * w1; lg[2] += gc * w2;
        m[3] += gd * w1; lg[3] += gd * w2;
    }

    float z[4];
    #pragma unroll
    for (int i = 0; i < 4; ++i)
        z[i] = act ? (eps[(size_t)(ur + i) * NCLASS + lane] * expf(lg[i]) + m[i]) : -1e30f;

    float zmax[4], s[4];
    #pragma unroll
    for (int i = 0; i < 4; ++i) zmax[i] = z[i];
    #pragma unroll
    for (int off = 32; off >= 1; off >>= 1) {
        #pragma unroll
        for (int i = 0; i < 4; ++i) zmax[i] = fmaxf(zmax[i], __shfl_xor(zmax[i], off));
    }
    #pragma unroll
    for (int i = 0; i < 4; ++i) s[i] = act ? expf(z[i] - zmax[i]) : 0.f;
    #pragma unroll
    for (int off = 32; off >= 1; off >>= 1) {
        #pragma unroll
        for (int i = 0; i < 4; ++i) s[i] += __shfl_xor(s[i], off);
    }
    if (act) {
        #pragma unroll
        for (int i = 0; i < 4; ++i)
            out[(size_t)(ur + i) * NCLASS + lane] = z[i] - zmax[i] - logf(s[i]);
    }
}

// ---------------- launcher --------------------------------------------------
extern "C" void kernel_launch(void* const* d_in, const int* in_sizes, int n_in,
                              void* d_out, int out_size, void* d_ws, size_t ws_size,
                              hipStream_t stream) {
    const float* x        = (const float*)d_in[0];
    const int*   edge_src = (const int*)d_in[1];
    const int*   edge_dst = (const int*)d_in[2];
    const float* edge_val = (const float*)d_in[3];
    const float* eps      = (const float*)d_in[4];
    const float* W1       = (const float*)d_in[5];
    const float* b1       = (const float*)d_in[6];
    const float* W11      = (const float*)d_in[7];
    const float* b11      = (const float*)d_in[8];
    const float* W12      = (const float*)d_in[9];
    const float* b12      = (const float*)d_in[10];
    float* out = (float*)d_out;

    // workspace layout: packed CSR first (8B-aligned), then dense temporaries
    int2*  csr     = (int2*)d_ws;                  // EDGES * 8B
    float* xw      = (float*)(csr + EDGES);        // NN*64
    float* h       = xw + (size_t)NN * NHID;       // NN*64
    int*   count   = (int*)(h + (size_t)NN * NHID);
    int*   tmp     = count + NN;
    int*   row_ptr = tmp + NN;                     // NN+1
    int*   cursor  = row_ptr + (NN + 1);
    int*   blocksum= cursor + NN;
    int*   blockoff= blocksum + 128;
    float* g2 = xw;                                // xw dead after spmm1

    const int NB = (NN + SCAN_BLK - 1) / SCAN_BLK; // 98

    k_gemm1<<<(NN + BM - 1) / BM, 256, 0, stream>>>(x, W1, xw);
    k_zero<<<(NN + 255) / 256, 256, 0, stream>>>(count);
    k_hist<<<(EDGES / 4 + 255) / 256, 256, 0, stream>>>(edge_dst, count);
    k_scanA<<<NB, SCAN_BLK, 0, stream>>>(count, tmp, blocksum);
    k_scanB<<<1, 128, 0, stream>>>(blocksum, blockoff, NB);
    k_scanC<<<(NN + 255) / 256, 256, 0, stream>>>(tmp, blockoff, count, row_ptr, cursor);
    k_scatter<<<(EDGES + 255) / 256, 256, 0, stream>>>(edge_src, edge_dst, edge_val,
                                                       cursor, csr);
    k_spmm<true><<<NN / 4, 256, 0, stream>>>(xw, row_ptr, csr, b1, h);
    k_spmm<false><<<NN / 4, 256, 0, stream>>>(h, row_ptr, csr, nullptr, g2);
    k_final<<<(NN / 4 + 3) / 4, 256, 0, stream>>>(g2, W11, b11, W12, b12, eps, out);
}